// Round 13
// baseline (400.161 us; speedup 1.0000x reference)
//
#include <hip/hip_runtime.h>

typedef __attribute__((ext_vector_type(4))) float  f32x4;
typedef __attribute__((ext_vector_type(8))) short  short8;
typedef __attribute__((ext_vector_type(4))) short  short4v;

#define M_TOK 8192
#define N_OUT 4096
#define K_IN  4096
#define NT    64          // K_IN / 64

typedef const __attribute__((address_space(1))) void* gp_t;
typedef __attribute__((address_space(3))) void* lp_t;
__device__ __forceinline__ void gl_lds16(const void* g, void* l) {
    __builtin_amdgcn_global_load_lds((gp_t)g, (lp_t)l, 16, 0, 0);
}

// ---------------- pre-pass: dequant qweight -> Wt[n][k] bf16 (transposed) ----------------
__global__ __launch_bounds__(256)
void dequant_w(const int* __restrict__ qweight, const int* __restrict__ qzeros,
               const float* __restrict__ scales, unsigned short* __restrict__ Wt) {
    const int k0 = blockIdx.x * 64;
    const int n0 = blockIdx.y * 64;
    const int t  = threadIdx.x;
    const int n  = t & 63;
    const int pl = t >> 6;
    const int g  = k0 >> 7;            // GROUPSIZE=128
    const int ncol = n0 + n;

    const float scale = scales[g * N_OUT + ncol];
    const int qz  = qzeros[g * (N_OUT / 8) + (ncol >> 3)];
    const int zp1 = ((qz >> ((ncol & 7) * 4)) & 0xF) + 1;
    const float zs = -(float)zp1 * scale;

    __shared__ unsigned short wt[64][80];

    const int p0 = k0 >> 3;
    #pragma unroll
    for (int i = 0; i < 2; ++i) {
        const int p_local = pl + i * 4;
        const int q = qweight[(size_t)(p0 + p_local) * N_OUT + ncol];
        union { short8 v; __bf16 h[8]; } u;
        #pragma unroll
        for (int j = 0; j < 8; ++j)
            u.h[j] = (__bf16)fmaf((float)((q >> (4 * j)) & 0xF), scale, zs);
        *(short8*)(&wt[n][8 * p_local]) = u.v;
    }
    __syncthreads();

    #pragma unroll
    for (int it = 0; it < 2; ++it) {
        const int row   = (t >> 3) + 32 * it;
        const int chunk = t & 7;
        short8 v = *(const short8*)(&wt[row][chunk * 8]);
        *(short8*)(Wt + (size_t)(n0 + row) * K_IN + k0 + chunk * 8) = v;
    }
}

// ---------------- main GEMM: 256x256, 4-phase (R7 schedule), A fp32->bf16 in-kernel ----------------
__global__ __launch_bounds__(512, 2)
void gemm_bf16_fx(const float* __restrict__ x,
                  const unsigned short* __restrict__ Wt,
                  const float* __restrict__ bias,
                  float* __restrict__ out)
{
    const int tid  = threadIdx.x;
    const int lane = tid & 63;
    const int wid  = tid >> 6;        // 0..7
    const int wm   = wid >> 2;        // 0..1
    const int wn   = wid & 3;         // 0..3

    // XCD swizzle: nwg = 512, 512 % 8 == 0 -> simple form bijective
    const int bid = blockIdx.x;
    const int swz = (bid & 7) * 64 + (bid >> 3);
    const int m0 = (swz >> 4) * 256;
    const int n0 = (swz & 15) * 256;

    __shared__ __align__(16) unsigned char lds[131072];
    unsigned char* Ab = lds;
    unsigned char* Bb = lds + 65536;

    f32x4 acc[8][4];
    #pragma unroll
    for (int i = 0; i < 8; ++i)
        #pragma unroll
        for (int j = 0; j < 4; ++j)
            acc[i][j] = f32x4{0.f, 0.f, 0.f, 0.f};

    // ---- staging constants (source col pre-swizzled; LDS dest linear) ----
    const int sw8    = ((tid & 7) ^ ((tid >> 3) & 7)) * 8;
    const int a_srow = tid >> 3;
    const int b_srow = (wid >> 2) * 64 + (wid & 3) * 8 + (lane >> 3);
    const int b_dst  = (wid >> 2) * 8192 + (wid & 3) * 1024;

    // ---- fragment-read constants (byte-col ^= (row&7)<<4, row&7 == lane&7) ----
    const int col0 = (((lane >> 4))     ^ (lane & 7)) << 4;
    const int col1 = ((4 | (lane >> 4)) ^ (lane & 7)) << 4;
    const int arow = (wm * 128 + (lane & 15)) * 128;
    const int brow = (wn * 64  + (lane & 15)) * 128;

    short8 af[4][2], b0[2][2], b1[2][2];
    f32x4 ra0[2][2], ra1[2][2];       // in-flight fp32 A (tile t+1), halves 0/1

#define CFENCE asm volatile("" ::: "memory")

// load fp32 A-half H of tile KT into RA (4 x f32x4 per thread)
#define LOADX(RA, KT, H) do { \
    _Pragma("unroll") for (int j_ = 0; j_ < 2; ++j_) \
    _Pragma("unroll") for (int q_ = 0; q_ < 2; ++q_) \
        RA[j_][q_] = *(const f32x4*)(x + (size_t)(m0 + j_ * 128 + (H) * 64 + a_srow) * K_IN \
                                       + (KT) * 64 + sw8 + q_ * 4); } while (0)

// convert RA -> bf16, ds_write into A section (SEL buffer, half H); layout == gl_lds dest
#define CVTW(RA, SEL, H) do { \
    _Pragma("unroll") for (int j_ = 0; j_ < 2; ++j_) { \
        union { short8 v; __bf16 h[8]; } u_; \
        u_.h[0] = (__bf16)RA[j_][0].x; u_.h[1] = (__bf16)RA[j_][0].y; \
        u_.h[2] = (__bf16)RA[j_][0].z; u_.h[3] = (__bf16)RA[j_][0].w; \
        u_.h[4] = (__bf16)RA[j_][1].x; u_.h[5] = (__bf16)RA[j_][1].y; \
        u_.h[6] = (__bf16)RA[j_][1].z; u_.h[7] = (__bf16)RA[j_][1].w; \
        *(short8*)(Ab + (SEL) * 32768 + j_ * 16384 + (H) * 8192 + tid * 16) = u_.v; } } while (0)

#define STAGE_B(SEL, KT, H) do { \
    _Pragma("unroll") for (int j_ = 0; j_ < 2; ++j_) \
        gl_lds16(Wt + (size_t)(n0 + j_ * 128 + (H) * 32 + b_srow) * K_IN + (KT) * 64 + sw8, \
                 Bb + (SEL) * 32768 + j_ * 16384 + (H) * 4096 + b_dst); } while (0)

#define LOAD_A(SEL, HM) do { \
    _Pragma("unroll") for (int mi_ = 0; mi_ < 4; ++mi_) { \
        af[mi_][0] = *(const short8*)(Ab + (SEL) * 32768 + arow + (HM) * 8192 + mi_ * 2048 + col0); \
        af[mi_][1] = *(const short8*)(Ab + (SEL) * 32768 + arow + (HM) * 8192 + mi_ * 2048 + col1); } } while (0)

#define LOAD_B(DST, SEL, HN) do { \
    _Pragma("unroll") for (int ni_ = 0; ni_ < 2; ++ni_) { \
        DST[ni_][0] = *(const short8*)(Bb + (SEL) * 32768 + brow + (HN) * 4096 + ni_ * 2048 + col0); \
        DST[ni_][1] = *(const short8*)(Bb + (SEL) * 32768 + brow + (HN) * 4096 + ni_ * 2048 + col1); } } while (0)

#define MFMA_Q(HM, HN, BF) do { \
    _Pragma("unroll") for (int mi_ = 0; mi_ < 4; ++mi_) \
    _Pragma("unroll") for (int ni_ = 0; ni_ < 2; ++ni_) \
    _Pragma("unroll") for (int kk_ = 0; kk_ < 2; ++kk_) \
        acc[(HM) * 4 + mi_][(HN) * 2 + ni_] = __builtin_amdgcn_mfma_f32_16x16x32_bf16( \
            af[mi_][kk_], BF[ni_][kk_], acc[(HM) * 4 + mi_][(HN) * 2 + ni_], 0, 0, 0); } while (0)

// A staged via ds_write (lgkm domain, visible next barrier); B via gl_lds.
// Single manual vmcnt(0) at F3 drains B gl_lds issued >=2 phases back.
// Compiler inserts vmcnt(2) before each CVTW (1-phase-old fp32 loads, L3-resident).
#define K_STEP(CUR, NXT) do { \
    /* F0: Q(0,0); issue next A0 fp32 loads + B0' gl_lds */ \
    LOAD_A(CUR, 0); \
    LOAD_B(b0, CUR, 0); \
    CFENCE; \
    LOADX(ra0, ktn, 0); \
    STAGE_B(NXT, ktn, 0); \
    __builtin_amdgcn_s_barrier(); \
    asm volatile("s_waitcnt lgkmcnt(0)" ::: "memory"); \
    __builtin_amdgcn_sched_barrier(0); \
    __builtin_amdgcn_s_setprio(1); \
    MFMA_Q(0, 0, b0); \
    __builtin_amdgcn_s_setprio(0); \
    /* F1: Q(0,1); cvt+write A0'; issue A1 fp32 loads + B1' gl_lds */ \
    LOAD_B(b1, CUR, 1); \
    CFENCE; \
    CVTW(ra0, NXT, 0); \
    CFENCE; \
    LOADX(ra1, ktn, 1); \
    STAGE_B(NXT, ktn, 1); \
    __builtin_amdgcn_s_barrier(); \
    asm volatile("s_waitcnt lgkmcnt(0)" ::: "memory"); \
    __builtin_amdgcn_sched_barrier(0); \
    __builtin_amdgcn_s_setprio(1); \
    MFMA_Q(0, 1, b1); \
    __builtin_amdgcn_s_setprio(0); \
    /* F2: Q(1,0); cvt+write A1' */ \
    LOAD_A(CUR, 1); \
    CFENCE; \
    CVTW(ra1, NXT, 1); \
    __builtin_amdgcn_s_barrier(); \
    asm volatile("s_waitcnt lgkmcnt(0)" ::: "memory"); \
    __builtin_amdgcn_sched_barrier(0); \
    __builtin_amdgcn_s_setprio(1); \
    MFMA_Q(1, 0, b0); \
    __builtin_amdgcn_s_setprio(0); \
    /* F3: Q(1,1); confirm all B staging for next tile */ \
    asm volatile("s_waitcnt vmcnt(0)" ::: "memory"); \
    __builtin_amdgcn_s_barrier(); \
    __builtin_amdgcn_sched_barrier(0); \
    __builtin_amdgcn_s_setprio(1); \
    MFMA_Q(1, 1, b1); \
    __builtin_amdgcn_s_setprio(0); \
} while (0)

    // prologue: tile 0 -> buf0 (A via reg-cvt-write, B via gl_lds), full drain
    LOADX(ra0, 0, 0);
    LOADX(ra1, 0, 1);
    CFENCE;
    STAGE_B(0, 0, 0);
    STAGE_B(0, 0, 1);
    CFENCE;
    CVTW(ra0, 0, 0);
    CVTW(ra1, 0, 1);
    asm volatile("s_waitcnt vmcnt(0) lgkmcnt(0)" ::: "memory");
    __builtin_amdgcn_s_barrier();

    int ktn;
    #pragma unroll 1
    for (int kt = 0; kt < NT; kt += 2) {
        ktn = kt + 1;
        K_STEP(0, 1);
        ktn = (kt + 2) & (NT - 1);   // last iter: redundant re-stage of tile 0 keeps counts exact
        K_STEP(1, 0);
    }

#undef LOADX
#undef CVTW
#undef STAGE_B
#undef LOAD_A
#undef LOAD_B
#undef MFMA_Q
#undef K_STEP
#undef CFENCE

    // epilogue
    const int col_base = n0 + wn * 64 + (lane & 15);
    const int row_base = m0 + wm * 128 + (lane >> 4) * 4;
    #pragma unroll
    for (int fn = 0; fn < 4; ++fn) {
        const int col = col_base + fn * 16;
        const float bv = bias[col];
        #pragma unroll
        for (int fm = 0; fm < 8; ++fm) {
            #pragma unroll
            for (int r = 0; r < 4; ++r) {
                const int row = row_base + fm * 16 + r;
                out[(size_t)row * N_OUT + col] = acc[fm][fn][r] + bv;
            }
        }
    }
}

// ---------------- fallback: fused kernel (if ws too small) ----------------
__global__ __launch_bounds__(256, 2)
void gptq_gemm_fused(const float* __restrict__ x,
                     const int*   __restrict__ qweight,
                     const int*   __restrict__ qzeros,
                     const float* __restrict__ scales,
                     const float* __restrict__ bias,
                     float*       __restrict__ out)
{
    const int tid  = threadIdx.x;
    const int lane = tid & 63;
    const int wid  = tid >> 6;
    const int wm   = wid >> 1;
    const int wn   = wid & 1;
    const int m0 = blockIdx.y * 128;
    const int n0 = blockIdx.x * 128;

    __shared__ __align__(16) unsigned char lds[32768];
    unsigned char* Ab = lds;
    unsigned char* Bb = lds + 16384;

    const int ar  = tid >> 4;
    const int ac4 = (tid & 15) * 4;
    const int bnn = tid & 127;
    const int bph = tid >> 7;
    const int ncol = n0 + bnn;

    f32x4 a_reg[8];
    int   q_reg[4];
    float scale_r = 0.f, zs_r = 0.f;

    f32x4 acc[4][4];
    #pragma unroll
    for (int i = 0; i < 4; ++i)
        #pragma unroll
        for (int j = 0; j < 4; ++j)
            acc[i][j] = f32x4{0.f, 0.f, 0.f, 0.f};

    auto load_tile = [&](int kt) {
        const int k0 = kt * 64;
        #pragma unroll
        for (int i = 0; i < 8; ++i)
            a_reg[i] = *(const f32x4*)(x + (size_t)(m0 + ar + 16 * i) * K_IN + k0 + ac4);
        const int p0 = k0 >> 3;
        #pragma unroll
        for (int i = 0; i < 4; ++i)
            q_reg[i] = qweight[(size_t)(p0 + i * 2 + bph) * N_OUT + ncol];
        const int g = k0 >> 7;
        scale_r = scales[g * N_OUT + ncol];
        const int qz = qzeros[g * (N_OUT / 8) + (ncol >> 3)];
        zs_r = -(float)(((qz >> ((ncol & 7) * 4)) & 0xF) + 1) * scale_r;
    };

    auto store_tile = [&]() {
        #pragma unroll
        for (int i = 0; i < 8; ++i) {
            const int r = ar + 16 * i;
            const int addr = r * 128 + ((ac4 * 2) ^ ((r & 7) << 4));
            union { short4v v; __bf16 h[4]; } u;
            u.h[0] = (__bf16)a_reg[i].x; u.h[1] = (__bf16)a_reg[i].y;
            u.h[2] = (__bf16)a_reg[i].z; u.h[3] = (__bf16)a_reg[i].w;
            *(short4v*)(Ab + addr) = u.v;
        }
        #pragma unroll
        for (int i = 0; i < 4; ++i) {
            const int pl = i * 2 + bph;
            const int q  = q_reg[i];
            union { short8 v; __bf16 h[8]; } u;
            #pragma unroll
            for (int j = 0; j < 8; ++j)
                u.h[j] = (__bf16)fmaf((float)((q >> (4 * j)) & 0xF), scale_r, zs_r);
            const int addr = bnn * 128 + ((pl * 16) ^ ((bnn & 7) << 4));
            *(short8*)(Bb + addr) = u.v;
        }
    };

    auto compute_tile = [&]() {
        #pragma unroll
        for (int kk = 0; kk < 2; ++kk) {
            short8 afr[4], bfr[4];
            const int cb = kk * 64 + (lane >> 4) * 16;
            #pragma unroll
            for (int mi = 0; mi < 4; ++mi) {
                const int r = wm * 64 + mi * 16 + (lane & 15);
                afr[mi] = *(const short8*)(Ab + r * 128 + (cb ^ ((r & 7) << 4)));
            }
            #pragma unroll
            for (int ni = 0; ni < 4; ++ni) {
                const int nn = wn * 64 + ni * 16 + (lane & 15);
                bfr[ni] = *(const short8*)(Bb + nn * 128 + (cb ^ ((nn & 7) << 4)));
            }
            #pragma unroll
            for (int mi = 0; mi < 4; ++mi)
                #pragma unroll
                for (int ni = 0; ni < 4; ++ni)
                    acc[mi][ni] = __builtin_amdgcn_mfma_f32_16x16x32_bf16(
                        afr[mi], bfr[ni], acc[mi][ni], 0, 0, 0);
        }
    };

    load_tile(0);
    for (int kt = 0; kt < 64; ++kt) {
        if (kt) __syncthreads();
        store_tile();
        __syncthreads();
        if (kt + 1 < 64) load_tile(kt + 1);
        compute_tile();
    }

    const int col_base = n0 + wn * 64 + (lane & 15);
    const int row_base = m0 + wm * 64 + (lane >> 4) * 4;
    #pragma unroll
    for (int ni = 0; ni < 4; ++ni) {
        const int col = col_base + ni * 16;
        const float bv = bias[col];
        #pragma unroll
        for (int mi = 0; mi < 4; ++mi)
            #pragma unroll
            for (int r = 0; r < 4; ++r)
                out[(size_t)(row_base + mi * 16 + r) * N_OUT + col] = acc[mi][ni][r] + bv;
    }
}

extern "C" void kernel_launch(void* const* d_in, const int* in_sizes, int n_in,
                              void* d_out, int out_size, void* d_ws, size_t ws_size,
                              hipStream_t stream) {
    const float* x       = (const float*)d_in[0];
    const int*   qweight = (const int*)  d_in[1];
    const int*   qzeros  = (const int*)  d_in[2];
    const float* scales  = (const float*)d_in[3];
    const float* bias    = (const float*)d_in[5];
    float* out = (float*)d_out;

    const size_t wt_bytes = (size_t)N_OUT * K_IN * 2;   // 32 MiB

    if (ws_size >= wt_bytes) {
        unsigned short* Wt = (unsigned short*)d_ws;
        dequant_w<<<dim3(K_IN / 64, N_OUT / 64), dim3(256), 0, stream>>>(qweight, qzeros, scales, Wt);
        gemm_bf16_fx<<<dim3((M_TOK / 256) * (N_OUT / 256)), dim3(512), 0, stream>>>(x, Wt, bias, out);
    } else {
        gptq_gemm_fused<<<dim3(N_OUT / 128, M_TOK / 128), dim3(256), 0, stream>>>(
            x, qweight, qzeros, scales, bias, out);
    }
}

// Round 14
// 255.714 us; speedup vs baseline: 1.5649x; 1.5649x over previous
//
#include <hip/hip_runtime.h>

typedef __attribute__((ext_vector_type(4))) float  f32x4;
typedef __attribute__((ext_vector_type(8))) short  short8;
typedef __attribute__((ext_vector_type(4))) short  short4v;

#define M_TOK 8192
#define N_OUT 4096
#define K_IN  4096
#define NT    64          // K_IN / 64

typedef const __attribute__((address_space(1))) void* gp_t;
typedef __attribute__((address_space(3))) void* lp_t;
__device__ __forceinline__ void gl_lds16(const void* g, void* l) {
    __builtin_amdgcn_global_load_lds((gp_t)g, (lp_t)l, 16, 0, 0);
}

// ---------------- pre-pass 1: x fp32 -> bf16 (BW-roofline: ~30 us) ----------------
__global__ __launch_bounds__(256)
void cvt_x(const float* __restrict__ x, unsigned short* __restrict__ xb) {
    const size_t i = ((size_t)blockIdx.x * 256 + threadIdx.x) * 8;
    f32x4 a = *(const f32x4*)(x + i);
    f32x4 b = *(const f32x4*)(x + i + 4);
    union { short8 v; __bf16 h[8]; } u;
    u.h[0] = (__bf16)a.x; u.h[1] = (__bf16)a.y; u.h[2] = (__bf16)a.z; u.h[3] = (__bf16)a.w;
    u.h[4] = (__bf16)b.x; u.h[5] = (__bf16)b.y; u.h[6] = (__bf16)b.z; u.h[7] = (__bf16)b.w;
    *(short8*)(xb + i) = u.v;
}

// ---------------- pre-pass 2: dequant qweight -> Wt[n][k] bf16 (transposed, ~7 us) ----------------
__global__ __launch_bounds__(256)
void dequant_w(const int* __restrict__ qweight, const int* __restrict__ qzeros,
               const float* __restrict__ scales, unsigned short* __restrict__ Wt) {
    const int k0 = blockIdx.x * 64;
    const int n0 = blockIdx.y * 64;
    const int t  = threadIdx.x;
    const int n  = t & 63;
    const int pl = t >> 6;
    const int g  = k0 >> 7;            // GROUPSIZE=128
    const int ncol = n0 + n;

    const float scale = scales[g * N_OUT + ncol];
    const int qz  = qzeros[g * (N_OUT / 8) + (ncol >> 3)];
    const int zp1 = ((qz >> ((ncol & 7) * 4)) & 0xF) + 1;
    const float zs = -(float)zp1 * scale;

    __shared__ unsigned short wt[64][80];

    const int p0 = k0 >> 3;
    #pragma unroll
    for (int i = 0; i < 2; ++i) {
        const int p_local = pl + i * 4;
        const int q = qweight[(size_t)(p0 + p_local) * N_OUT + ncol];
        union { short8 v; __bf16 h[8]; } u;
        #pragma unroll
        for (int j = 0; j < 8; ++j)
            u.h[j] = (__bf16)fmaf((float)((q >> (4 * j)) & 0xF), scale, zs);
        *(short8*)(&wt[n][8 * p_local]) = u.v;
    }
    __syncthreads();

    #pragma unroll
    for (int it = 0; it < 2; ++it) {
        const int row   = (t >> 3) + 32 * it;
        const int chunk = t & 7;
        short8 v = *(const short8*)(&wt[row][chunk * 8]);
        *(short8*)(Wt + (size_t)(n0 + row) * K_IN + k0 + chunk * 8) = v;
    }
}

// ---------------- main GEMM: 256x256 tile, 4-phase, reads-before-barrier (R7 optimum) ----------------
// Measured: 222-224 us, MfmaUtil 57%, 0 bank conflicts. Schedule invariant (11 variants tested):
// reads+stages issued BEFORE the barrier; wait in phase P covers the reads of phase P+1
// (vmcnt targets loads issued 3-4 phases back); stages spread 4/2/2/0 across phases.
__global__ __launch_bounds__(512, 2)
void gemm_bf16_ph(const unsigned short* __restrict__ xb,
                  const unsigned short* __restrict__ Wt,
                  const float* __restrict__ bias,
                  float* __restrict__ out)
{
    const int tid  = threadIdx.x;
    const int lane = tid & 63;
    const int wid  = tid >> 6;        // 0..7
    const int wm   = wid >> 2;        // 0..1
    const int wn   = wid & 3;         // 0..3

    // XCD swizzle: nwg = 512, 512 % 8 == 0 -> simple form bijective
    const int bid = blockIdx.x;
    const int swz = (bid & 7) * 64 + (bid >> 3);
    const int m0 = (swz >> 4) * 256;
    const int n0 = (swz & 15) * 256;

    __shared__ __align__(16) unsigned char lds[131072];
    unsigned char* Ab = lds;
    unsigned char* Bb = lds + 65536;

    f32x4 acc[8][4];
    #pragma unroll
    for (int i = 0; i < 8; ++i)
        #pragma unroll
        for (int j = 0; j < 4; ++j)
            acc[i][j] = f32x4{0.f, 0.f, 0.f, 0.f};

    // ---- staging constants (source col pre-swizzled; LDS dest linear — rule #21) ----
    const int sw8    = ((tid & 7) ^ ((tid >> 3) & 7)) * 8;
    const int a_srow = tid >> 3;
    const int b_srow = (wid >> 2) * 64 + (wid & 3) * 8 + (lane >> 3);
    const int a_dst  = wid * 1024;
    const int b_dst  = (wid >> 2) * 8192 + (wid & 3) * 1024;

    // ---- fragment-read constants (byte-col ^= (row&7)<<4, row&7 == lane&7) ----
    const int col0 = (((lane >> 4))     ^ (lane & 7)) << 4;
    const int col1 = ((4 | (lane >> 4)) ^ (lane & 7)) << 4;
    const int arow = (wm * 128 + (lane & 15)) * 128;
    const int brow = (wn * 64  + (lane & 15)) * 128;

    short8 af[4][2], b0[2][2], b1[2][2];

#define CFENCE asm volatile("" ::: "memory")

#define STAGE_A(SEL, KT, H) do { \
    _Pragma("unroll") for (int j_ = 0; j_ < 2; ++j_) \
        gl_lds16(xb + (size_t)(m0 + j_ * 128 + (H) * 64 + a_srow) * K_IN + (KT) * 64 + sw8, \
                 Ab + (SEL) * 32768 + j_ * 16384 + (H) * 8192 + a_dst); } while (0)

#define STAGE_B(SEL, KT, H) do { \
    _Pragma("unroll") for (int j_ = 0; j_ < 2; ++j_) \
        gl_lds16(Wt + (size_t)(n0 + j_ * 128 + (H) * 32 + b_srow) * K_IN + (KT) * 64 + sw8, \
                 Bb + (SEL) * 32768 + j_ * 16384 + (H) * 4096 + b_dst); } while (0)

#define LOAD_A(SEL, HM) do { \
    _Pragma("unroll") for (int mi_ = 0; mi_ < 4; ++mi_) { \
        af[mi_][0] = *(const short8*)(Ab + (SEL) * 32768 + arow + (HM) * 8192 + mi_ * 2048 + col0); \
        af[mi_][1] = *(const short8*)(Ab + (SEL) * 32768 + arow + (HM) * 8192 + mi_ * 2048 + col1); } } while (0)

#define LOAD_B(DST, SEL, HN) do { \
    _Pragma("unroll") for (int ni_ = 0; ni_ < 2; ++ni_) { \
        DST[ni_][0] = *(const short8*)(Bb + (SEL) * 32768 + brow + (HN) * 4096 + ni_ * 2048 + col0); \
        DST[ni_][1] = *(const short8*)(Bb + (SEL) * 32768 + brow + (HN) * 4096 + ni_ * 2048 + col1); } } while (0)

#define MFMA_Q(HM, HN, BF) do { \
    _Pragma("unroll") for (int mi_ = 0; mi_ < 4; ++mi_) \
    _Pragma("unroll") for (int ni_ = 0; ni_ < 2; ++ni_) \
    _Pragma("unroll") for (int kk_ = 0; kk_ < 2; ++kk_) \
        acc[(HM) * 4 + mi_][(HN) * 2 + ni_] = __builtin_amdgcn_mfma_f32_16x16x32_bf16( \
            af[mi_][kk_], BF[ni_][kk_], acc[(HM) * 4 + mi_][(HN) * 2 + ni_], 0, 0, 0); } while (0)

// Phase = {reads for this quadrant; stage next-tile unit; vmcnt(N) for a load
// issued 3 phases ahead; barrier; drain own reads; MFMA}.
#define K_STEP(CUR, NXT) do { \
    /* F0: Q(0,0) */ \
    LOAD_A(CUR, 0); \
    LOAD_B(b0, CUR, 0); \
    CFENCE; \
    STAGE_A(NXT, ktn, 0); \
    STAGE_B(NXT, ktn, 0); \
    asm volatile("s_waitcnt vmcnt(6)" ::: "memory"); \
    __builtin_amdgcn_s_barrier(); \
    asm volatile("s_waitcnt lgkmcnt(0)" ::: "memory"); \
    __builtin_amdgcn_sched_barrier(0); \
    __builtin_amdgcn_s_setprio(1); \
    MFMA_Q(0, 0, b0); \
    __builtin_amdgcn_s_setprio(0); \
    /* F1: Q(0,1) */ \
    LOAD_B(b1, CUR, 1); \
    CFENCE; \
    STAGE_B(NXT, ktn, 1); \
    asm volatile("s_waitcnt vmcnt(6)" ::: "memory"); \
    __builtin_amdgcn_s_barrier(); \
    asm volatile("s_waitcnt lgkmcnt(0)" ::: "memory"); \
    __builtin_amdgcn_sched_barrier(0); \
    __builtin_amdgcn_s_setprio(1); \
    MFMA_Q(0, 1, b1); \
    __builtin_amdgcn_s_setprio(0); \
    /* F2: Q(1,0) */ \
    LOAD_A(CUR, 1); \
    CFENCE; \
    STAGE_A(NXT, ktn, 1); \
    __builtin_amdgcn_s_barrier(); \
    asm volatile("s_waitcnt lgkmcnt(0)" ::: "memory"); \
    __builtin_amdgcn_sched_barrier(0); \
    __builtin_amdgcn_s_setprio(1); \
    MFMA_Q(1, 0, b0); \
    __builtin_amdgcn_s_setprio(0); \
    /* F3: Q(1,1); vmcnt(4) gates next F0's reads (A0',B0' issued 3-4 phases back) */ \
    asm volatile("s_waitcnt vmcnt(4)" ::: "memory"); \
    __builtin_amdgcn_s_barrier(); \
    __builtin_amdgcn_sched_barrier(0); \
    __builtin_amdgcn_s_setprio(1); \
    MFMA_Q(1, 1, b1); \
    __builtin_amdgcn_s_setprio(0); \
} while (0)

    // prologue: stage tile 0 into buf0, FIFO order A0,B0,B1,A1; gate A0,B0
    STAGE_A(0, 0, 0);
    CFENCE;
    STAGE_B(0, 0, 0);
    CFENCE;
    STAGE_B(0, 0, 1);
    CFENCE;
    STAGE_A(0, 0, 1);
    asm volatile("s_waitcnt vmcnt(4)" ::: "memory");
    __builtin_amdgcn_s_barrier();

    int ktn;
    #pragma unroll 1
    for (int kt = 0; kt < NT; kt += 2) {
        ktn = kt + 1;
        K_STEP(0, 1);
        ktn = (kt + 2) & (NT - 1);   // last iter: redundant re-stage of tile 0 keeps counts exact
        K_STEP(1, 0);
    }

#undef STAGE_A
#undef STAGE_B
#undef LOAD_A
#undef LOAD_B
#undef MFMA_Q
#undef K_STEP
#undef CFENCE

    // epilogue
    const int col_base = n0 + wn * 64 + (lane & 15);
    const int row_base = m0 + wm * 128 + (lane >> 4) * 4;
    #pragma unroll
    for (int fn = 0; fn < 4; ++fn) {
        const int col = col_base + fn * 16;
        const float bv = bias[col];
        #pragma unroll
        for (int fm = 0; fm < 8; ++fm) {
            #pragma unroll
            for (int r = 0; r < 4; ++r) {
                const int row = row_base + fm * 16 + r;
                out[(size_t)row * N_OUT + col] = acc[fm][fn][r] + bv;
            }
        }
    }
}

// ---------------- fallback: fused kernel (if ws too small) ----------------
__global__ __launch_bounds__(256, 2)
void gptq_gemm_fused(const float* __restrict__ x,
                     const int*   __restrict__ qweight,
                     const int*   __restrict__ qzeros,
                     const float* __restrict__ scales,
                     const float* __restrict__ bias,
                     float*       __restrict__ out)
{
    const int tid  = threadIdx.x;
    const int lane = tid & 63;
    const int wid  = tid >> 6;
    const int wm   = wid >> 1;
    const int wn   = wid & 1;
    const int m0 = blockIdx.y * 128;
    const int n0 = blockIdx.x * 128;

    __shared__ __align__(16) unsigned char lds[32768];
    unsigned char* Ab = lds;
    unsigned char* Bb = lds + 16384;

    const int ar  = tid >> 4;
    const int ac4 = (tid & 15) * 4;
    const int bnn = tid & 127;
    const int bph = tid >> 7;
    const int ncol = n0 + bnn;

    f32x4 a_reg[8];
    int   q_reg[4];
    float scale_r = 0.f, zs_r = 0.f;

    f32x4 acc[4][4];
    #pragma unroll
    for (int i = 0; i < 4; ++i)
        #pragma unroll
        for (int j = 0; j < 4; ++j)
            acc[i][j] = f32x4{0.f, 0.f, 0.f, 0.f};

    auto load_tile = [&](int kt) {
        const int k0 = kt * 64;
        #pragma unroll
        for (int i = 0; i < 8; ++i)
            a_reg[i] = *(const f32x4*)(x + (size_t)(m0 + ar + 16 * i) * K_IN + k0 + ac4);
        const int p0 = k0 >> 3;
        #pragma unroll
        for (int i = 0; i < 4; ++i)
            q_reg[i] = qweight[(size_t)(p0 + i * 2 + bph) * N_OUT + ncol];
        const int g = k0 >> 7;
        scale_r = scales[g * N_OUT + ncol];
        const int qz = qzeros[g * (N_OUT / 8) + (ncol >> 3)];
        zs_r = -(float)(((qz >> ((ncol & 7) * 4)) & 0xF) + 1) * scale_r;
    };

    auto store_tile = [&]() {
        #pragma unroll
        for (int i = 0; i < 8; ++i) {
            const int r = ar + 16 * i;
            const int addr = r * 128 + ((ac4 * 2) ^ ((r & 7) << 4));
            union { short4v v; __bf16 h[4]; } u;
            u.h[0] = (__bf16)a_reg[i].x; u.h[1] = (__bf16)a_reg[i].y;
            u.h[2] = (__bf16)a_reg[i].z; u.h[3] = (__bf16)a_reg[i].w;
            *(short4v*)(Ab + addr) = u.v;
        }
        #pragma unroll
        for (int i = 0; i < 4; ++i) {
            const int pl = i * 2 + bph;
            const int q  = q_reg[i];
            union { short8 v; __bf16 h[8]; } u;
            #pragma unroll
            for (int j = 0; j < 8; ++j)
                u.h[j] = (__bf16)fmaf((float)((q >> (4 * j)) & 0xF), scale_r, zs_r);
            const int addr = bnn * 128 + ((pl * 16) ^ ((bnn & 7) << 4));
            *(short8*)(Bb + addr) = u.v;
        }
    };

    auto compute_tile = [&]() {
        #pragma unroll
        for (int kk = 0; kk < 2; ++kk) {
            short8 afr[4], bfr[4];
            const int cb = kk * 64 + (lane >> 4) * 16;
            #pragma unroll
            for (int mi = 0; mi < 4; ++mi) {
                const int r = wm * 64 + mi * 16 + (lane & 15);
                afr[mi] = *(const short8*)(Ab + r * 128 + (cb ^ ((r & 7) << 4)));
            }
            #pragma unroll
            for (int ni = 0; ni < 4; ++ni) {
                const int nn = wn * 64 + ni * 16 + (lane & 15);
                bfr[ni] = *(const short8*)(Bb + nn * 128 + (cb ^ ((nn & 7) << 4)));
            }
            #pragma unroll
            for (int mi = 0; mi < 4; ++mi)
                #pragma unroll
                for (int ni = 0; ni < 4; ++ni)
                    acc[mi][ni] = __builtin_amdgcn_mfma_f32_16x16x32_bf16(
                        afr[mi], bfr[ni], acc[mi][ni], 0, 0, 0);
        }
    };

    load_tile(0);
    for (int kt = 0; kt < 64; ++kt) {
        if (kt) __syncthreads();
        store_tile();
        __syncthreads();
        if (kt + 1 < 64) load_tile(kt + 1);
        compute_tile();
    }

    const int col_base = n0 + wn * 64 + (lane & 15);
    const int row_base = m0 + wm * 64 + (lane >> 4) * 4;
    #pragma unroll
    for (int ni = 0; ni < 4; ++ni) {
        const int col = col_base + ni * 16;
        const float bv = bias[col];
        #pragma unroll
        for (int mi = 0; mi < 4; ++mi)
            #pragma unroll
            for (int r = 0; r < 4; ++r)
                out[(size_t)(row_base + mi * 16 + r) * N_OUT + col] = acc[mi][ni][r] + bv;
    }
}

extern "C" void kernel_launch(void* const* d_in, const int* in_sizes, int n_in,
                              void* d_out, int out_size, void* d_ws, size_t ws_size,
                              hipStream_t stream) {
    const float* x       = (const float*)d_in[0];
    const int*   qweight = (const int*)  d_in[1];
    const int*   qzeros  = (const int*)  d_in[2];
    const float* scales  = (const float*)d_in[3];
    const float* bias    = (const float*)d_in[5];
    float* out = (float*)d_out;

    const size_t xb_bytes = (size_t)M_TOK * K_IN * 2;   // 64 MiB
    const size_t wt_bytes = (size_t)N_OUT * K_IN * 2;   // 32 MiB

    if (ws_size >= xb_bytes + wt_bytes) {
        unsigned short* xb = (unsigned short*)d_ws;
        unsigned short* Wt = (unsigned short*)((char*)d_ws + xb_bytes);
        cvt_x<<<dim3((M_TOK * K_IN) / (256 * 8)), dim3(256), 0, stream>>>(x, xb);
        dequant_w<<<dim3(K_IN / 64, N_OUT / 64), dim3(256), 0, stream>>>(qweight, qzeros, scales, Wt);
        gemm_bf16_ph<<<dim3((M_TOK / 256) * (N_OUT / 256)), dim3(512), 0, stream>>>(xb, Wt, bias, out);
    } else {
        gptq_gemm_fused<<<dim3(N_OUT / 128, M_TOK / 128), dim3(256), 0, stream>>>(
            x, qweight, qzeros, scales, bias, out);
    }
}